// Round 5
// baseline (288.315 us; speedup 1.0000x reference)
//
#include <hip/hip_runtime.h>
#include <hip/hip_fp16.h>

#define HID 32
#define BN 131         // nodes per bucket -> NBr = ceil(100000/131) = 764
#define NBPAD 768      // padded bucket arrays (3 per thread in binscatter scan)
#define BSTRIDE 4608   // per-bucket edge capacity: mean 4188 + 6.5 sigma
#define CHUNK 6144     // edges per binscatter chunk (512 thr * EPT)
#define EPT 12         // edges/thread carried in registers
#define CPAD 16        // cursor padding: one counter per 64B line
#define NSPLIT 3       // agg: blocks per bucket (node-range slices)
#define HNMAX 44       // max nodes per slice (131 = 44+44+43)
#define LPCAP 1700     // slice edge capacity: mean 1408 + 7.8 sigma

__device__ __forceinline__ float lrelu(float x) { return x > 0.0f ? x : 0.2f * x; }

// ---------------- transform (layer-1 dense) ----------------

__global__ void k_transform1(const float* __restrict__ x,
                             const float* __restrict__ W1,
                             const float* __restrict__ att_src,
                             const float* __restrict__ att_dst,
                             __half* __restrict__ hh,
                             float* __restrict__ a_s,
                             float* __restrict__ a_d,
                             int* __restrict__ cursor, int N)
{
    int tid = blockIdx.x * blockDim.x + threadIdx.x;
    if (tid < NBPAD * CPAD) cursor[tid] = 0;
    int n = tid >> 5, f = tid & 31;
    if (n >= N) return;
    float x0 = x[n * 3 + 0], x1 = x[n * 3 + 1], x2 = x[n * 3 + 2];
    float hv = x0 * W1[f] + x1 * W1[HID + f] + x2 * W1[2 * HID + f];
    hh[(size_t)n * HID + f] = __float2half(hv);
    float as = hv * att_src[f];
    float ad = hv * att_dst[f];
    #pragma unroll
    for (int m = 16; m >= 1; m >>= 1) {
        as += __shfl_xor(as, m, 32);
        ad += __shfl_xor(ad, m, 32);
    }
    if (f == 0) { a_s[n] = as; a_d[n] = ad; }
}

// ---------------- binscatter (R3 form: reg-carried, padded cursors) -------

struct BinSM {
    int stage[CHUNK];                 // 24 KB
    unsigned short sbid[CHUNK];       // 12 KB
    int lhist[NBPAD], lexcl[NBPAD], lbase[NBPAD], lcur[NBPAD];  // 12 KB
    int arr[256];                     // 1 KB
};                                    // ~49 KB -> 3 blocks/CU

__global__ void __launch_bounds__(512) k_binscatter(const int* __restrict__ src,
        const int* __restrict__ dst, int* __restrict__ cursor,
        unsigned int* __restrict__ packed, int NBr, int E)
{
    __shared__ BinSM S;
    int t = threadIdx.x;
    int base = blockIdx.x * CHUNK;
    int cnt = E - base; if (cnt > CHUNK) cnt = CHUNK;

    for (int i = t; i < NBPAD; i += 512) { S.lhist[i] = 0; S.lcur[i] = 0; }
    __syncthreads();

    int myd[EPT], mys[EPT];
    #pragma unroll
    for (int u = 0; u < EPT; ++u) {
        int i = t + u * 512;
        myd[u] = -1;
        if (i < cnt) { myd[u] = dst[base + i]; mys[u] = src[base + i]; }
    }
    #pragma unroll
    for (int u = 0; u < EPT; ++u)
        if (myd[u] >= 0) atomicAdd(&S.lhist[myd[u] / BN], 1);
    __syncthreads();

    int b0 = 3 * t;
    int c0 = 0, c1 = 0, c2 = 0, s = 0;
    if (t < 256) {
        c0 = S.lhist[b0]; c1 = S.lhist[b0 + 1]; c2 = S.lhist[b0 + 2];
        s = c0 + c1 + c2;
        S.arr[t] = s;
    }
    __syncthreads();
    for (int o = 1; o < 256; o <<= 1) {
        int v = (t < 256 && t >= o) ? S.arr[t - o] : 0;
        __syncthreads();
        if (t < 256) S.arr[t] += v;
        __syncthreads();
    }
    if (t < 256) {
        int ex = S.arr[t] - s;
        int e0 = ex, e1 = ex + c0, e2 = ex + c0 + c1;
        S.lexcl[b0] = e0; S.lexcl[b0 + 1] = e1; S.lexcl[b0 + 2] = e2;
        for (int i = 0; i < c0; ++i) S.sbid[e0 + i] = (unsigned short)b0;
        for (int i = 0; i < c1; ++i) S.sbid[e1 + i] = (unsigned short)(b0 + 1);
        for (int i = 0; i < c2; ++i) S.sbid[e2 + i] = (unsigned short)(b0 + 2);
    }
    for (int b = t; b < NBr; b += 512)
        if (S.lhist[b])
            S.lbase[b] = b * BSTRIDE + atomicAdd(&cursor[b * CPAD], S.lhist[b]);
    __syncthreads();

    #pragma unroll
    for (int u = 0; u < EPT; ++u) {
        if (myd[u] >= 0) {
            int d = myd[u];
            int b = d / BN;
            int dl = d - b * BN;
            int idx = S.lexcl[b] + atomicAdd(&S.lcur[b], 1);
            S.stage[idx] = (int)((unsigned)mys[u] | ((unsigned)dl << 17));
        }
    }
    __syncthreads();

    for (int i = t; i < cnt; i += 512) {
        int b = S.sbid[i];
        int gpos = S.lbase[b] + (i - S.lexcl[b]);
        if (gpos < (b + 1) * BSTRIDE)
            packed[gpos] = (unsigned)S.stage[i];
    }
}

// ---------------- agg building blocks (R0 loop, sliced buckets) ----------

struct AggSM {
    int2  lpair[LPCAP];               // 13.6 KB: .x = src, .y = exp bits
    int   hist[64], scn[64], cur[64]; // 768 B
    float adT[HNMAX];                 // 176 B
};                                    // ~14.5 KB -> 8 blocks/CU (thread-capped)

// build CSR+exp for one 44-node slice of a bucket; streams the full bucket.
__device__ __forceinline__ void build_slice(AggSM& S,
        const unsigned int* __restrict__ pk, int cnt,
        const float* __restrict__ a_s, const float* __restrict__ a_d,
        int nodeBase, int dlo, int HN, int N)
{
    int t = threadIdx.x;
    if (t < 64) { S.hist[t] = 0; S.cur[t] = 0; }
    if (t < HN) { int n = nodeBase + dlo + t; S.adT[t] = (n < N) ? a_d[n] : 0.0f; }
    __syncthreads();
    for (int i = t; i < cnt; i += 256) {
        unsigned ldl = ((pk[i] >> 17) & 255) - (unsigned)dlo;
        if (ldl < (unsigned)HN) atomicAdd(&S.hist[ldl], 1);
    }
    __syncthreads();
    if (t < 64) S.scn[t] = S.hist[t];
    __syncthreads();
    for (int o = 1; o < 64; o <<= 1) {
        int v = (t < 64 && t >= o) ? S.scn[t - o] : 0;
        __syncthreads();
        if (t < 64) S.scn[t] += v;
        __syncthreads();
    }
    for (int i = t; i < cnt; i += 256) {
        unsigned p = pk[i];
        unsigned ldl = ((p >> 17) & 255) - (unsigned)dlo;
        if (ldl < (unsigned)HN) {
            int sv = (int)(p & 0x1FFFF);
            float e = __expf(lrelu(a_s[sv] + S.adT[ldl]));
            int pos = atomicAdd(&S.cur[ldl], 1);
            int idx = (S.scn[ldl] - S.hist[ldl]) + pos;
            if (idx < LPCAP) S.lpair[idx] = make_int2(sv, __float_as_int(e));
        }
    }
    __syncthreads();
}

// agg inner loop (R0-proven): 16 lanes/node, 2 features/lane, half2 loads,
// broadcast b64 LDS pair read, den in-loop, unroll x8.
__device__ __forceinline__ void agg_node(const __half* __restrict__ hh,
                                         float ex_self, const float* __restrict__ b,
                                         int n, int f,
                                         const int2* lpair,
                                         int off, int dg, float& vx, float& vy)
{
    float den = ex_self;
    float2 hs = __half22float2(*(const __half2*)(hh + (size_t)n * HID + 2 * f));
    float accx = ex_self * hs.x;
    float accy = ex_self * hs.y;
    int j = 0;
    for (; j + 8 <= dg; j += 8) {
        int2 p0 = lpair[off + j + 0], p1 = lpair[off + j + 1];
        int2 p2 = lpair[off + j + 2], p3 = lpair[off + j + 3];
        int2 p4 = lpair[off + j + 4], p5 = lpair[off + j + 5];
        int2 p6 = lpair[off + j + 6], p7 = lpair[off + j + 7];
        __half2 h0 = *(const __half2*)(hh + (size_t)p0.x * HID + 2 * f);
        __half2 h1 = *(const __half2*)(hh + (size_t)p1.x * HID + 2 * f);
        __half2 h2 = *(const __half2*)(hh + (size_t)p2.x * HID + 2 * f);
        __half2 h3 = *(const __half2*)(hh + (size_t)p3.x * HID + 2 * f);
        __half2 h4 = *(const __half2*)(hh + (size_t)p4.x * HID + 2 * f);
        __half2 h5 = *(const __half2*)(hh + (size_t)p5.x * HID + 2 * f);
        __half2 h6 = *(const __half2*)(hh + (size_t)p6.x * HID + 2 * f);
        __half2 h7 = *(const __half2*)(hh + (size_t)p7.x * HID + 2 * f);
        float e0 = __int_as_float(p0.y), e1 = __int_as_float(p1.y);
        float e2 = __int_as_float(p2.y), e3 = __int_as_float(p3.y);
        float e4 = __int_as_float(p4.y), e5 = __int_as_float(p5.y);
        float e6 = __int_as_float(p6.y), e7 = __int_as_float(p7.y);
        float2 q0 = __half22float2(h0), q1 = __half22float2(h1);
        float2 q2 = __half22float2(h2), q3 = __half22float2(h3);
        float2 q4 = __half22float2(h4), q5 = __half22float2(h5);
        float2 q6 = __half22float2(h6), q7 = __half22float2(h7);
        den += ((e0 + e1) + (e2 + e3)) + ((e4 + e5) + (e6 + e7));
        accx = fmaf(e0, q0.x, accx); accy = fmaf(e0, q0.y, accy);
        accx = fmaf(e1, q1.x, accx); accy = fmaf(e1, q1.y, accy);
        accx = fmaf(e2, q2.x, accx); accy = fmaf(e2, q2.y, accy);
        accx = fmaf(e3, q3.x, accx); accy = fmaf(e3, q3.y, accy);
        accx = fmaf(e4, q4.x, accx); accy = fmaf(e4, q4.y, accy);
        accx = fmaf(e5, q5.x, accx); accy = fmaf(e5, q5.y, accy);
        accx = fmaf(e6, q6.x, accx); accy = fmaf(e6, q6.y, accy);
        accx = fmaf(e7, q7.x, accx); accy = fmaf(e7, q7.y, accy);
    }
    for (; j < dg; ++j) {
        int2 p0 = lpair[off + j];
        float e0 = __int_as_float(p0.y);
        float2 q0 = __half22float2(*(const __half2*)(hh + (size_t)p0.x * HID + 2 * f));
        den += e0;
        accx = fmaf(e0, q0.x, accx);
        accy = fmaf(e0, q0.y, accy);
    }
    float inv = 1.0f / (den + 1e-16f);
    vx = fmaxf(accx * inv + b[2 * f], 0.0f);
    vy = fmaxf(accy * inv + b[2 * f + 1], 0.0f);
}

// layer-1 epilogue: W2 transform + layer-2 attention halves (width-16)
__device__ __forceinline__ void epi_mid(int n, int f, float vx, float vy,
        const float* __restrict__ W2, const float* __restrict__ as2w,
        const float* __restrict__ ad2w,
        __half* __restrict__ hh_out, float* __restrict__ as_out,
        float* __restrict__ ad_out)
{
    float hx = 0.0f, hy = 0.0f;
    #pragma unroll
    for (int k = 0; k < 16; ++k) {
        float va = __shfl(vx, k, 16);
        float vb = __shfl(vy, k, 16);
        float2 w0 = *(const float2*)(W2 + (2 * k) * HID + 2 * f);
        float2 w1 = *(const float2*)(W2 + (2 * k + 1) * HID + 2 * f);
        hx = fmaf(va, w0.x, hx); hy = fmaf(va, w0.y, hy);
        hx = fmaf(vb, w1.x, hx); hy = fmaf(vb, w1.y, hy);
    }
    *(__half2*)(hh_out + (size_t)n * HID + 2 * f) = __floats2half2_rn(hx, hy);
    float as = hx * as2w[2 * f] + hy * as2w[2 * f + 1];
    float ad = hx * ad2w[2 * f] + hy * ad2w[2 * f + 1];
    #pragma unroll
    for (int m2 = 8; m2 >= 1; m2 >>= 1) {
        as += __shfl_xor(as, m2, 16);
        ad += __shfl_xor(ad, m2, 16);
    }
    if (f == 0) { as_out[n] = as; ad_out[n] = ad; }
}

// ---------------- agg kernels (256 threads, 3 slices per bucket) ---------

__global__ void __launch_bounds__(256, 8) k_agg_mid(const __half* __restrict__ hh,
        const float* __restrict__ a_s, const float* __restrict__ a_d,
        const int* __restrict__ cursor, const unsigned int* __restrict__ packed,
        const float* __restrict__ b1, const float* __restrict__ W2,
        const float* __restrict__ as2w, const float* __restrict__ ad2w,
        __half* __restrict__ hh_out, float* __restrict__ as_out,
        float* __restrict__ ad_out, int N)
{
    __shared__ AggSM S;
    int bid = blockIdx.x, t = threadIdx.x;
    int bk = bid / NSPLIT, k = bid - NSPLIT * bk;
    int dlo = k * HNMAX;
    int HN = BN - dlo; if (HN > HNMAX) HN = HNMAX;
    int cnt = cursor[bk * CPAD]; if (cnt > BSTRIDE) cnt = BSTRIDE;
    build_slice(S, packed + (size_t)bk * BSTRIDE, cnt, a_s, a_d, bk * BN, dlo, HN, N);
    int g = t >> 4, f = t & 15;
    for (int ldl = g; ldl < HN; ldl += 16) {
        int n = bk * BN + dlo + ldl;
        if (n >= N) continue;
        int off = S.scn[ldl] - S.hist[ldl];
        int dg = S.hist[ldl];
        if (off + dg > LPCAP) dg = LPCAP - off;
        float exs = __expf(lrelu(a_s[n] + S.adT[ldl]));
        float vx, vy;
        agg_node(hh, exs, b1, n, f, S.lpair, off, dg, vx, vy);
        epi_mid(n, f, vx, vy, W2, as2w, ad2w, hh_out, as_out, ad_out);
    }
}

__global__ void __launch_bounds__(256, 8) k_agg_out(const __half* __restrict__ hh,
        const float* __restrict__ a_s, const float* __restrict__ a_d,
        const int* __restrict__ cursor, const unsigned int* __restrict__ packed,
        const float* __restrict__ b2, const float* __restrict__ Wl,
        const float* __restrict__ bl, float* __restrict__ out, int N)
{
    __shared__ AggSM S;
    int bid = blockIdx.x, t = threadIdx.x;
    int bk = bid / NSPLIT, k = bid - NSPLIT * bk;
    int dlo = k * HNMAX;
    int HN = BN - dlo; if (HN > HNMAX) HN = HNMAX;
    int cnt = cursor[bk * CPAD]; if (cnt > BSTRIDE) cnt = BSTRIDE;
    build_slice(S, packed + (size_t)bk * BSTRIDE, cnt, a_s, a_d, bk * BN, dlo, HN, N);
    int g = t >> 4, f = t & 15;
    for (int ldl = g; ldl < HN; ldl += 16) {
        int n = bk * BN + dlo + ldl;
        if (n >= N) continue;
        int off = S.scn[ldl] - S.hist[ldl];
        int dg = S.hist[ldl];
        if (off + dg > LPCAP) dg = LPCAP - off;
        float exs = __expf(lrelu(a_s[n] + S.adT[ldl]));
        float vx, vy;
        agg_node(hh, exs, b2, n, f, S.lpair, off, dg, vx, vy);
        float y = vx * Wl[2 * f] + vy * Wl[2 * f + 1];
        #pragma unroll
        for (int m2 = 8; m2 >= 1; m2 >>= 1)
            y += __shfl_xor(y, m2, 16);
        if (f == 0) out[n] = y + bl[0];
    }
}

// ---------------- host ----------------

extern "C" void kernel_launch(void* const* d_in, const int* in_sizes, int n_in,
                              void* d_out, int out_size, void* d_ws, size_t ws_size,
                              hipStream_t stream)
{
    const float* x        = (const float*)d_in[0];
    const int*   eidx     = (const int*)d_in[1];
    const float* W1       = (const float*)d_in[2];
    const float* att_src1 = (const float*)d_in[3];
    const float* att_dst1 = (const float*)d_in[4];
    const float* b1       = (const float*)d_in[5];
    const float* W2       = (const float*)d_in[6];
    const float* att_src2 = (const float*)d_in[7];
    const float* att_dst2 = (const float*)d_in[8];
    const float* b2       = (const float*)d_in[9];
    const float* Wl       = (const float*)d_in[10];
    const float* bl       = (const float*)d_in[11];
    float* out = (float*)d_out;

    int N = in_sizes[0] / 3;
    int E = in_sizes[1] / 2;
    const int* src = eidx;
    const int* dst = eidx + E;
    int NBr = (N + BN - 1) / BN;   // 764

    size_t szNHh = (size_t)N * HID * 2;          // 6.4 MB
    size_t szN4  = (size_t)N * 4;
    size_t szPK  = (size_t)NBr * BSTRIDE * 4;    // 14.1 MB

    char* ws = (char*)d_ws;
    __half* h1h    = (__half*)ws; ws += szNHh;
    __half* h2h    = (__half*)ws; ws += szNHh;
    unsigned int* packed = (unsigned int*)ws; ws += szPK;
    float*  a_s1   = (float*)ws;  ws += szN4;
    float*  a_d1   = (float*)ws;  ws += szN4;
    float*  a_s2   = (float*)ws;  ws += szN4;
    float*  a_d2   = (float*)ws;  ws += szN4;
    int*    cursor = (int*)ws;    ws += (size_t)NBPAD * CPAD * 4;

    const int B = 256;
    int gridNode32 = (N * HID + B - 1) / B;
    int gridBin    = (E + CHUNK - 1) / CHUNK;
    int gridAgg    = NBr * NSPLIT;               // 2292

    k_transform1<<<gridNode32, B, 0, stream>>>(x, W1, att_src1, att_dst1,
                                               h1h, a_s1, a_d1, cursor, N);
    k_binscatter<<<gridBin, 512, 0, stream>>>(src, dst, cursor, packed, NBr, E);
    k_agg_mid<<<gridAgg, 256, 0, stream>>>(h1h, a_s1, a_d1, cursor, packed,
                                           b1, W2, att_src2, att_dst2,
                                           h2h, a_s2, a_d2, N);
    k_agg_out<<<gridAgg, 256, 0, stream>>>(h2h, a_s2, a_d2, cursor, packed,
                                           b2, Wl, bl, out, N);
}

// Round 6
// 248.600 us; speedup vs baseline: 1.1598x; 1.1598x over previous
//
#include <hip/hip_runtime.h>
#include <hip/hip_fp16.h>

#define HID 32
#define BN 131         // nodes per bucket -> NBr = ceil(100000/131) = 764
#define NBPAD 768      // padded bucket arrays (3 per thread in binscatter scan)
#define BSTRIDE 4608   // per-bucket edge capacity: mean 4188 + 6.5 sigma
#define CHUNK 6144     // edges per binscatter chunk (512 thr * EPT)
#define EPT 12         // edges/thread carried in registers
#define CPAD 16        // cursor padding: one counter per 64B line

__device__ __forceinline__ float lrelu(float x) { return x > 0.0f ? x : 0.2f * x; }

// ---------------- transform (layer-1 dense) ----------------

__global__ void k_transform1(const float* __restrict__ x,
                             const float* __restrict__ W1,
                             const float* __restrict__ att_src,
                             const float* __restrict__ att_dst,
                             __half* __restrict__ hh,
                             float* __restrict__ a_s,
                             float* __restrict__ a_d,
                             int* __restrict__ cursor, int N)
{
    int tid = blockIdx.x * blockDim.x + threadIdx.x;
    if (tid < NBPAD * CPAD) cursor[tid] = 0;
    int n = tid >> 5, f = tid & 31;
    if (n >= N) return;
    float x0 = x[n * 3 + 0], x1 = x[n * 3 + 1], x2 = x[n * 3 + 2];
    float hv = x0 * W1[f] + x1 * W1[HID + f] + x2 * W1[2 * HID + f];
    hh[(size_t)n * HID + f] = __float2half(hv);
    float as = hv * att_src[f];
    float ad = hv * att_dst[f];
    #pragma unroll
    for (int m = 16; m >= 1; m >>= 1) {
        as += __shfl_xor(as, m, 32);
        ad += __shfl_xor(ad, m, 32);
    }
    if (f == 0) { a_s[n] = as; a_d[n] = ad; }
}

// ---------------- binscatter (R3 form: reg-carried, padded cursors) -------
// Proven correct in R3/R5; single src/dst read pass; coalesced run writes.

struct BinSM {
    int stage[CHUNK];                 // 24 KB
    unsigned short sbid[CHUNK];       // 12 KB
    int lhist[NBPAD], lexcl[NBPAD], lbase[NBPAD], lcur[NBPAD];  // 12 KB
    int arr[256];                     // 1 KB
};                                    // ~49 KB -> 3 blocks/CU

__global__ void __launch_bounds__(512) k_binscatter(const int* __restrict__ src,
        const int* __restrict__ dst, int* __restrict__ cursor,
        unsigned int* __restrict__ packed, int NBr, int E)
{
    __shared__ BinSM S;
    int t = threadIdx.x;
    int base = blockIdx.x * CHUNK;
    int cnt = E - base; if (cnt > CHUNK) cnt = CHUNK;

    for (int i = t; i < NBPAD; i += 512) { S.lhist[i] = 0; S.lcur[i] = 0; }
    __syncthreads();

    int myd[EPT], mys[EPT];
    #pragma unroll
    for (int u = 0; u < EPT; ++u) {
        int i = t + u * 512;
        myd[u] = -1;
        if (i < cnt) { myd[u] = dst[base + i]; mys[u] = src[base + i]; }
    }
    #pragma unroll
    for (int u = 0; u < EPT; ++u)
        if (myd[u] >= 0) atomicAdd(&S.lhist[myd[u] / BN], 1);
    __syncthreads();

    int b0 = 3 * t;
    int c0 = 0, c1 = 0, c2 = 0, s = 0;
    if (t < 256) {
        c0 = S.lhist[b0]; c1 = S.lhist[b0 + 1]; c2 = S.lhist[b0 + 2];
        s = c0 + c1 + c2;
        S.arr[t] = s;
    }
    __syncthreads();
    for (int o = 1; o < 256; o <<= 1) {
        int v = (t < 256 && t >= o) ? S.arr[t - o] : 0;
        __syncthreads();
        if (t < 256) S.arr[t] += v;
        __syncthreads();
    }
    if (t < 256) {
        int ex = S.arr[t] - s;
        int e0 = ex, e1 = ex + c0, e2 = ex + c0 + c1;
        S.lexcl[b0] = e0; S.lexcl[b0 + 1] = e1; S.lexcl[b0 + 2] = e2;
        for (int i = 0; i < c0; ++i) S.sbid[e0 + i] = (unsigned short)b0;
        for (int i = 0; i < c1; ++i) S.sbid[e1 + i] = (unsigned short)(b0 + 1);
        for (int i = 0; i < c2; ++i) S.sbid[e2 + i] = (unsigned short)(b0 + 2);
    }
    for (int b = t; b < NBr; b += 512)
        if (S.lhist[b])
            S.lbase[b] = b * BSTRIDE + atomicAdd(&cursor[b * CPAD], S.lhist[b]);
    __syncthreads();

    #pragma unroll
    for (int u = 0; u < EPT; ++u) {
        if (myd[u] >= 0) {
            int d = myd[u];
            int b = d / BN;
            int dl = d - b * BN;
            int idx = S.lexcl[b] + atomicAdd(&S.lcur[b], 1);
            S.stage[idx] = (int)((unsigned)mys[u] | ((unsigned)dl << 17));
        }
    }
    __syncthreads();

    for (int i = t; i < cnt; i += 512) {
        int b = S.sbid[i];
        int gpos = S.lbase[b] + (i - S.lexcl[b]);
        if (gpos < (b + 1) * BSTRIDE)
            packed[gpos] = (unsigned)S.stage[i];
    }
}

// ---------------- agg building blocks (R0 structure) ----------------

struct AggSM {
    int2  lpair[BSTRIDE];                     // 36.9 KB: .x = src, .y = exp bits
    int   lhist[256], lscan[256], lcur[256];  // 3 KB
    float adT[BN];                            // 0.5 KB
};                                            // ~40 KB -> grid-limited 3 blocks/CU

// in-block CSR+exp build (R0-proven form), 512 threads
__device__ __forceinline__ void build_csr(AggSM& S,
        const unsigned int* __restrict__ pk, int cnt,
        const float* __restrict__ a_s, const float* __restrict__ a_d,
        int nodeBase, int N)
{
    int t = threadIdx.x;
    if (t < 256) { S.lhist[t] = 0; S.lcur[t] = 0; }
    if (t < BN) { int n = nodeBase + t; S.adT[t] = (n < N) ? a_d[n] : 0.0f; }
    __syncthreads();
    for (int i = t; i < cnt; i += 512)
        atomicAdd(&S.lhist[(pk[i] >> 17) & 255], 1);
    __syncthreads();
    if (t < 256) S.lscan[t] = S.lhist[t];
    __syncthreads();
    for (int o = 1; o < 256; o <<= 1) {
        int v = (t < 256 && t >= o) ? S.lscan[t - o] : 0;
        __syncthreads();
        if (t < 256) S.lscan[t] += v;
        __syncthreads();
    }
    for (int i = t; i < cnt; i += 512) {
        unsigned p = pk[i];
        int dl = (p >> 17) & 255;
        int sv = (int)(p & 0x1FFFF);
        float e = __expf(lrelu(a_s[sv] + S.adT[dl]));
        int pos = atomicAdd(&S.lcur[dl], 1);
        S.lpair[(S.lscan[dl] - S.lhist[dl]) + pos] = make_int2(sv, __float_as_int(e));
    }
    __syncthreads();
}

// agg inner loop: 16 lanes/node, 2 feats/lane, TWO-STAGE SOFTWARE PIPELINE —
// gathers for edges j+8..j+15 are issued BEFORE the FMAs that consume
// j..j+7, doubling in-flight loads per group (8 -> 16) to cover latency.
__device__ __forceinline__ void agg_node(const __half* __restrict__ hh,
                                         float ex_self, const float* __restrict__ b,
                                         int n, int f,
                                         const int2* lpair,
                                         int off, int dg, float& vx, float& vy)
{
    float den = ex_self;
    float2 hs = __half22float2(*(const __half2*)(hh + (size_t)n * HID + 2 * f));
    float accx = ex_self * hs.x;
    float accy = ex_self * hs.y;
    int j = 0;
    if (dg >= 16) {
        // preload stage (edges 0..7)
        float e0, e1, e2, e3, e4, e5, e6, e7;
        __half2 g0, g1, g2, g3, g4, g5, g6, g7;
        {
            int2 p0 = lpair[off + 0], p1 = lpair[off + 1];
            int2 p2 = lpair[off + 2], p3 = lpair[off + 3];
            int2 p4 = lpair[off + 4], p5 = lpair[off + 5];
            int2 p6 = lpair[off + 6], p7 = lpair[off + 7];
            g0 = *(const __half2*)(hh + (size_t)p0.x * HID + 2 * f);
            g1 = *(const __half2*)(hh + (size_t)p1.x * HID + 2 * f);
            g2 = *(const __half2*)(hh + (size_t)p2.x * HID + 2 * f);
            g3 = *(const __half2*)(hh + (size_t)p3.x * HID + 2 * f);
            g4 = *(const __half2*)(hh + (size_t)p4.x * HID + 2 * f);
            g5 = *(const __half2*)(hh + (size_t)p5.x * HID + 2 * f);
            g6 = *(const __half2*)(hh + (size_t)p6.x * HID + 2 * f);
            g7 = *(const __half2*)(hh + (size_t)p7.x * HID + 2 * f);
            e0 = __int_as_float(p0.y); e1 = __int_as_float(p1.y);
            e2 = __int_as_float(p2.y); e3 = __int_as_float(p3.y);
            e4 = __int_as_float(p4.y); e5 = __int_as_float(p5.y);
            e6 = __int_as_float(p6.y); e7 = __int_as_float(p7.y);
        }
        for (; j + 16 <= dg; j += 8) {
            // issue next batch (j+8 .. j+15) FIRST
            int jb = off + j + 8;
            int2 p0 = lpair[jb + 0], p1 = lpair[jb + 1];
            int2 p2 = lpair[jb + 2], p3 = lpair[jb + 3];
            int2 p4 = lpair[jb + 4], p5 = lpair[jb + 5];
            int2 p6 = lpair[jb + 6], p7 = lpair[jb + 7];
            __half2 t0 = *(const __half2*)(hh + (size_t)p0.x * HID + 2 * f);
            __half2 t1 = *(const __half2*)(hh + (size_t)p1.x * HID + 2 * f);
            __half2 t2 = *(const __half2*)(hh + (size_t)p2.x * HID + 2 * f);
            __half2 t3 = *(const __half2*)(hh + (size_t)p3.x * HID + 2 * f);
            __half2 t4 = *(const __half2*)(hh + (size_t)p4.x * HID + 2 * f);
            __half2 t5 = *(const __half2*)(hh + (size_t)p5.x * HID + 2 * f);
            __half2 t6 = *(const __half2*)(hh + (size_t)p6.x * HID + 2 * f);
            __half2 t7 = *(const __half2*)(hh + (size_t)p7.x * HID + 2 * f);
            float u0 = __int_as_float(p0.y), u1 = __int_as_float(p1.y);
            float u2 = __int_as_float(p2.y), u3 = __int_as_float(p3.y);
            float u4 = __int_as_float(p4.y), u5 = __int_as_float(p5.y);
            float u6 = __int_as_float(p6.y), u7 = __int_as_float(p7.y);
            // consume current batch
            float2 c0 = __half22float2(g0), c1 = __half22float2(g1);
            float2 c2 = __half22float2(g2), c3 = __half22float2(g3);
            float2 c4 = __half22float2(g4), c5 = __half22float2(g5);
            float2 c6 = __half22float2(g6), c7 = __half22float2(g7);
            den += ((e0 + e1) + (e2 + e3)) + ((e4 + e5) + (e6 + e7));
            accx = fmaf(e0, c0.x, accx); accy = fmaf(e0, c0.y, accy);
            accx = fmaf(e1, c1.x, accx); accy = fmaf(e1, c1.y, accy);
            accx = fmaf(e2, c2.x, accx); accy = fmaf(e2, c2.y, accy);
            accx = fmaf(e3, c3.x, accx); accy = fmaf(e3, c3.y, accy);
            accx = fmaf(e4, c4.x, accx); accy = fmaf(e4, c4.y, accy);
            accx = fmaf(e5, c5.x, accx); accy = fmaf(e5, c5.y, accy);
            accx = fmaf(e6, c6.x, accx); accy = fmaf(e6, c6.y, accy);
            accx = fmaf(e7, c7.x, accx); accy = fmaf(e7, c7.y, accy);
            // rotate stage
            e0 = u0; e1 = u1; e2 = u2; e3 = u3;
            e4 = u4; e5 = u5; e6 = u6; e7 = u7;
            g0 = t0; g1 = t1; g2 = t2; g3 = t3;
            g4 = t4; g5 = t5; g6 = t6; g7 = t7;
        }
        {   // drain final preloaded batch
            float2 c0 = __half22float2(g0), c1 = __half22float2(g1);
            float2 c2 = __half22float2(g2), c3 = __half22float2(g3);
            float2 c4 = __half22float2(g4), c5 = __half22float2(g5);
            float2 c6 = __half22float2(g6), c7 = __half22float2(g7);
            den += ((e0 + e1) + (e2 + e3)) + ((e4 + e5) + (e6 + e7));
            accx = fmaf(e0, c0.x, accx); accy = fmaf(e0, c0.y, accy);
            accx = fmaf(e1, c1.x, accx); accy = fmaf(e1, c1.y, accy);
            accx = fmaf(e2, c2.x, accx); accy = fmaf(e2, c2.y, accy);
            accx = fmaf(e3, c3.x, accx); accy = fmaf(e3, c3.y, accy);
            accx = fmaf(e4, c4.x, accx); accy = fmaf(e4, c4.y, accy);
            accx = fmaf(e5, c5.x, accx); accy = fmaf(e5, c5.y, accy);
            accx = fmaf(e6, c6.x, accx); accy = fmaf(e6, c6.y, accy);
            accx = fmaf(e7, c7.x, accx); accy = fmaf(e7, c7.y, accy);
        }
        j += 8;
    }
    for (; j < dg; ++j) {
        int2 p0 = lpair[off + j];
        float ee = __int_as_float(p0.y);
        float2 cc = __half22float2(*(const __half2*)(hh + (size_t)p0.x * HID + 2 * f));
        den += ee;
        accx = fmaf(ee, cc.x, accx);
        accy = fmaf(ee, cc.y, accy);
    }
    float inv = 1.0f / (den + 1e-16f);
    vx = fmaxf(accx * inv + b[2 * f], 0.0f);
    vy = fmaxf(accy * inv + b[2 * f + 1], 0.0f);
}

// layer-1 epilogue: W2 transform + layer-2 attention halves (width-16)
__device__ __forceinline__ void epi_mid(int n, int f, float vx, float vy,
        const float* __restrict__ W2, const float* __restrict__ as2w,
        const float* __restrict__ ad2w,
        __half* __restrict__ hh_out, float* __restrict__ as_out,
        float* __restrict__ ad_out)
{
    float hx = 0.0f, hy = 0.0f;
    #pragma unroll
    for (int k = 0; k < 16; ++k) {
        float va = __shfl(vx, k, 16);
        float vb = __shfl(vy, k, 16);
        float2 w0 = *(const float2*)(W2 + (2 * k) * HID + 2 * f);
        float2 w1 = *(const float2*)(W2 + (2 * k + 1) * HID + 2 * f);
        hx = fmaf(va, w0.x, hx); hy = fmaf(va, w0.y, hy);
        hx = fmaf(vb, w1.x, hx); hy = fmaf(vb, w1.y, hy);
    }
    *(__half2*)(hh_out + (size_t)n * HID + 2 * f) = __floats2half2_rn(hx, hy);
    float as = hx * as2w[2 * f] + hy * as2w[2 * f + 1];
    float ad = hx * ad2w[2 * f] + hy * ad2w[2 * f + 1];
    #pragma unroll
    for (int m2 = 8; m2 >= 1; m2 >>= 1) {
        as += __shfl_xor(as, m2, 16);
        ad += __shfl_xor(ad, m2, 16);
    }
    if (f == 0) { as_out[n] = as; ad_out[n] = ad; }
}

// ---------------- agg kernels (R0 geometry: 512 thr, one block/bucket) ----

__global__ void __launch_bounds__(512) k_agg_mid(const __half* __restrict__ hh,
        const float* __restrict__ a_s, const float* __restrict__ a_d,
        const int* __restrict__ cursor, const unsigned int* __restrict__ packed,
        const float* __restrict__ b1, const float* __restrict__ W2,
        const float* __restrict__ as2w, const float* __restrict__ ad2w,
        __half* __restrict__ hh_out, float* __restrict__ as_out,
        float* __restrict__ ad_out, int N)
{
    __shared__ AggSM S;
    int bk = blockIdx.x, t = threadIdx.x;
    int cnt = cursor[bk * CPAD]; if (cnt > BSTRIDE) cnt = BSTRIDE;
    build_csr(S, packed + (size_t)bk * BSTRIDE, cnt, a_s, a_d, bk * BN, N);
    int g = t >> 4, f = t & 15;
    for (int dl = g; dl < BN; dl += 32) {
        int n = bk * BN + dl;
        if (n >= N) continue;
        int off = S.lscan[dl] - S.lhist[dl];
        int dg = S.lhist[dl];
        float exs = __expf(lrelu(a_s[n] + S.adT[dl]));
        float vx, vy;
        agg_node(hh, exs, b1, n, f, S.lpair, off, dg, vx, vy);
        epi_mid(n, f, vx, vy, W2, as2w, ad2w, hh_out, as_out, ad_out);
    }
}

__global__ void __launch_bounds__(512) k_agg_out(const __half* __restrict__ hh,
        const float* __restrict__ a_s, const float* __restrict__ a_d,
        const int* __restrict__ cursor, const unsigned int* __restrict__ packed,
        const float* __restrict__ b2, const float* __restrict__ Wl,
        const float* __restrict__ bl, float* __restrict__ out, int N)
{
    __shared__ AggSM S;
    int bk = blockIdx.x, t = threadIdx.x;
    int cnt = cursor[bk * CPAD]; if (cnt > BSTRIDE) cnt = BSTRIDE;
    build_csr(S, packed + (size_t)bk * BSTRIDE, cnt, a_s, a_d, bk * BN, N);
    int g = t >> 4, f = t & 15;
    for (int dl = g; dl < BN; dl += 32) {
        int n = bk * BN + dl;
        if (n >= N) continue;
        int off = S.lscan[dl] - S.lhist[dl];
        int dg = S.lhist[dl];
        float exs = __expf(lrelu(a_s[n] + S.adT[dl]));
        float vx, vy;
        agg_node(hh, exs, b2, n, f, S.lpair, off, dg, vx, vy);
        float y = vx * Wl[2 * f] + vy * Wl[2 * f + 1];
        #pragma unroll
        for (int m2 = 8; m2 >= 1; m2 >>= 1)
            y += __shfl_xor(y, m2, 16);
        if (f == 0) out[n] = y + bl[0];
    }
}

// ---------------- host ----------------

extern "C" void kernel_launch(void* const* d_in, const int* in_sizes, int n_in,
                              void* d_out, int out_size, void* d_ws, size_t ws_size,
                              hipStream_t stream)
{
    const float* x        = (const float*)d_in[0];
    const int*   eidx     = (const int*)d_in[1];
    const float* W1       = (const float*)d_in[2];
    const float* att_src1 = (const float*)d_in[3];
    const float* att_dst1 = (const float*)d_in[4];
    const float* b1       = (const float*)d_in[5];
    const float* W2       = (const float*)d_in[6];
    const float* att_src2 = (const float*)d_in[7];
    const float* att_dst2 = (const float*)d_in[8];
    const float* b2       = (const float*)d_in[9];
    const float* Wl       = (const float*)d_in[10];
    const float* bl       = (const float*)d_in[11];
    float* out = (float*)d_out;

    int N = in_sizes[0] / 3;
    int E = in_sizes[1] / 2;
    const int* src = eidx;
    const int* dst = eidx + E;
    int NBr = (N + BN - 1) / BN;   // 764

    size_t szNHh = (size_t)N * HID * 2;          // 6.4 MB
    size_t szN4  = (size_t)N * 4;
    size_t szPK  = (size_t)NBr * BSTRIDE * 4;    // 14.1 MB

    char* ws = (char*)d_ws;
    __half* h1h    = (__half*)ws; ws += szNHh;
    __half* h2h    = (__half*)ws; ws += szNHh;
    unsigned int* packed = (unsigned int*)ws; ws += szPK;
    float*  a_s1   = (float*)ws;  ws += szN4;
    float*  a_d1   = (float*)ws;  ws += szN4;
    float*  a_s2   = (float*)ws;  ws += szN4;
    float*  a_d2   = (float*)ws;  ws += szN4;
    int*    cursor = (int*)ws;    ws += (size_t)NBPAD * CPAD * 4;

    const int B = 256;
    int gridNode32 = (N * HID + B - 1) / B;
    int gridBin    = (E + CHUNK - 1) / CHUNK;

    k_transform1<<<gridNode32, B, 0, stream>>>(x, W1, att_src1, att_dst1,
                                               h1h, a_s1, a_d1, cursor, N);
    k_binscatter<<<gridBin, 512, 0, stream>>>(src, dst, cursor, packed, NBr, E);
    k_agg_mid<<<NBr, 512, 0, stream>>>(h1h, a_s1, a_d1, cursor, packed,
                                       b1, W2, att_src2, att_dst2,
                                       h2h, a_s2, a_d2, N);
    k_agg_out<<<NBr, 512, 0, stream>>>(h2h, a_s2, a_d2, cursor, packed,
                                       b2, Wl, bl, out, N);
}